// Round 1
// baseline (1783.359 us; speedup 1.0000x reference)
//
#include <hip/hip_runtime.h>

#define DN 5
#define DE 4
#define DM 10

// ---------------------------------------------------------------------------
// k1: per-node projections.  ps[n][10] = node_attr[n] @ W[0:5,:] + b
//                            pd[n][10] = node_attr[n] @ W[5:10,:]
// ---------------------------------------------------------------------------
__global__ __launch_bounds__(256) void node_proj_kernel(
    const float* __restrict__ node_attr,
    const float* __restrict__ w_mpl,   // [14][10] row-major
    const float* __restrict__ b_mpl,   // [10]
    float* __restrict__ ps, float* __restrict__ pd, int N)
{
    __shared__ float sw[110];          // rows 0..9 of w_mpl (100) + bias (10)
    int t = threadIdx.x;
    if (t < 100)      sw[t] = w_mpl[t];
    else if (t < 110) sw[t] = b_mpl[t - 100];
    __syncthreads();

    int n = blockIdx.x * blockDim.x + t;
    if (n >= N) return;

    float a[DN];
#pragma unroll
    for (int k = 0; k < DN; ++k) a[k] = node_attr[(size_t)n * DN + k];

    float vs[DM], vd[DM];
#pragma unroll
    for (int j = 0; j < DM; ++j) { vs[j] = sw[100 + j]; vd[j] = 0.f; }
#pragma unroll
    for (int k = 0; k < DN; ++k)
#pragma unroll
        for (int j = 0; j < DM; ++j) {
            vs[j] = fmaf(a[k], sw[k * DM + j],       vs[j]);
            vd[j] = fmaf(a[k], sw[(DN + k) * DM + j], vd[j]);
        }

    float2* psv = reinterpret_cast<float2*>(ps + (size_t)n * DM); // 40B rows, 8B aligned
    float2* pdv = reinterpret_cast<float2*>(pd + (size_t)n * DM);
#pragma unroll
    for (int h = 0; h < 5; ++h) {
        psv[h] = make_float2(vs[2 * h], vs[2 * h + 1]);
        pdv[h] = make_float2(vd[2 * h], vd[2 * h + 1]);
    }
}

// ---------------------------------------------------------------------------
// k2: edge kernel.  msg = relu(ps[src] + pd[dst] + edge_attr @ W[10:14,:])
//     scatter-sum into xacc[dst].  Grid-stride; W_e held in 40 VGPRs.
// ---------------------------------------------------------------------------
__global__ __launch_bounds__(256) void edge_kernel(
    const int* __restrict__ ei,          // [2][E]
    const float* __restrict__ edge_attr, // [E][4]
    const float* __restrict__ w_mpl,
    const float* __restrict__ ps, const float* __restrict__ pd,
    float* __restrict__ xacc, int E)
{
    float we[DE][DM];
#pragma unroll
    for (int k = 0; k < DE; ++k)
#pragma unroll
        for (int j = 0; j < DM; ++j) we[k][j] = w_mpl[(2 * DN + k) * DM + j];

    int stride = gridDim.x * blockDim.x;
    for (int e = blockIdx.x * blockDim.x + threadIdx.x; e < E; e += stride) {
        int s = ei[e];
        int d = ei[(size_t)E + e];
        float4 ea = reinterpret_cast<const float4*>(edge_attr)[e];

        const float2* psv = reinterpret_cast<const float2*>(ps + (size_t)s * DM);
        const float2* pdv = reinterpret_cast<const float2*>(pd + (size_t)d * DM);

        float m[DM];
#pragma unroll
        for (int h = 0; h < 5; ++h) {
            float2 va = psv[h], vb = pdv[h];
            m[2 * h]     = va.x + vb.x;
            m[2 * h + 1] = va.y + vb.y;
        }

        float* xrow = xacc + (size_t)d * DM;
#pragma unroll
        for (int j = 0; j < DM; ++j) {
            float v = m[j];
            v = fmaf(ea.x, we[0][j], v);
            v = fmaf(ea.y, we[1][j], v);
            v = fmaf(ea.z, we[2][j], v);
            v = fmaf(ea.w, we[3][j], v);
            // ReLU: ~half the components are exactly 0 -> skip the atomic
            if (v > 0.f) unsafeAtomicAdd(&xrow[j], v);
        }
    }
}

// ---------------------------------------------------------------------------
// k3: node MLP head + scatter into per-graph accumulator
// ---------------------------------------------------------------------------
__global__ __launch_bounds__(256) void node_mlp_kernel(
    const float* __restrict__ xacc, const int* __restrict__ batch,
    const float* __restrict__ w1, const float* __restrict__ b1,
    const float* __restrict__ w2, const float* __restrict__ b2,
    float* __restrict__ gacc, int N)
{
    __shared__ float s1[100], sb1[10], s2[50], sb2[5];
    int t = threadIdx.x;
    if (t < 100)      s1[t] = w1[t];
    else if (t < 110) sb1[t - 100] = b1[t - 100];
    else if (t < 160) s2[t - 110] = w2[t - 110];
    else if (t < 165) sb2[t - 160] = b2[t - 160];
    __syncthreads();

    int n = blockIdx.x * blockDim.x + t;
    if (n >= N) return;

    float x[DM];
    const float2* xv = reinterpret_cast<const float2*>(xacc + (size_t)n * DM);
#pragma unroll
    for (int h = 0; h < 5; ++h) { float2 v = xv[h]; x[2 * h] = v.x; x[2 * h + 1] = v.y; }

    float h1[10];
#pragma unroll
    for (int j = 0; j < 10; ++j) h1[j] = sb1[j];
#pragma unroll
    for (int k = 0; k < 10; ++k)
#pragma unroll
        for (int j = 0; j < 10; ++j) h1[j] = fmaf(x[k], s1[k * 10 + j], h1[j]);
#pragma unroll
    for (int j = 0; j < 10; ++j) h1[j] = fmaxf(h1[j], 0.f);

    float h2[5];
#pragma unroll
    for (int j = 0; j < 5; ++j) h2[j] = sb2[j];
#pragma unroll
    for (int k = 0; k < 10; ++k)
#pragma unroll
        for (int j = 0; j < 5; ++j) h2[j] = fmaf(h1[k], s2[k * 5 + j], h2[j]);

    int g = batch[n];
    float* grow = gacc + (size_t)g * 5;
#pragma unroll
    for (int j = 0; j < 5; ++j) {
        float v = fmaxf(h2[j], 0.f);
        if (v > 0.f) unsafeAtomicAdd(&grow[j], v);
    }
}

// ---------------------------------------------------------------------------
// k4: per-graph head:  out = relu(g @ w3 + b3) @ w4 + b4
// ---------------------------------------------------------------------------
__global__ __launch_bounds__(256) void graph_head_kernel(
    const float* __restrict__ gacc,
    const float* __restrict__ w3, const float* __restrict__ b3,
    const float* __restrict__ w4, const float* __restrict__ b4,
    float* __restrict__ out, int G)
{
    __shared__ float s3[25], sb3[5], s4[5], sb4[1];
    int t = threadIdx.x;
    if (t < 25)      s3[t] = w3[t];
    else if (t < 30) sb3[t - 25] = b3[t - 25];
    else if (t < 35) s4[t - 30] = w4[t - 30];
    else if (t == 35) sb4[0] = b4[0];
    __syncthreads();

    int g = blockIdx.x * blockDim.x + t;
    if (g >= G) return;

    float x[5];
#pragma unroll
    for (int k = 0; k < 5; ++k) x[k] = gacc[(size_t)g * 5 + k];

    float o = sb4[0];
#pragma unroll
    for (int j = 0; j < 5; ++j) {
        float h = sb3[j];
#pragma unroll
        for (int k = 0; k < 5; ++k) h = fmaf(x[k], s3[k * 5 + j], h);
        h = fmaxf(h, 0.f);
        o = fmaf(h, s4[j], o);
    }
    out[g] = o;
}

// ---------------------------------------------------------------------------
extern "C" void kernel_launch(void* const* d_in, const int* in_sizes, int n_in,
                              void* d_out, int out_size, void* d_ws, size_t ws_size,
                              hipStream_t stream)
{
    const int*   ei        = (const int*)d_in[0];
    const float* node_attr = (const float*)d_in[1];
    const float* edge_attr = (const float*)d_in[2];
    const int*   batch     = (const int*)d_in[3];
    // d_in[4] = num_graphs (scalar), unused — G comes from out_size
    const float* w_mpl = (const float*)d_in[5];
    const float* b_mpl = (const float*)d_in[6];
    const float* w1    = (const float*)d_in[7];
    const float* b1    = (const float*)d_in[8];
    const float* w2    = (const float*)d_in[9];
    const float* b2    = (const float*)d_in[10];
    const float* w3    = (const float*)d_in[11];
    const float* b3    = (const float*)d_in[12];
    const float* w4    = (const float*)d_in[13];
    const float* b4    = (const float*)d_in[14];
    float* out = (float*)d_out;

    const int E = in_sizes[0] / 2;
    const int N = in_sizes[1] / DN;
    const int G = out_size;

    // workspace layout (floats): [xacc N*10][gacc G*5][ps N*10][pd N*10]
    float* ws   = (float*)d_ws;
    float* xacc = ws;
    float* gacc = xacc + (size_t)N * DM;
    float* ps   = gacc + (size_t)G * 5;
    float* pd   = ps   + (size_t)N * DM;

    // zero the two accumulators (ws is poisoned 0xAA before every launch)
    hipMemsetAsync(d_ws, 0, ((size_t)N * DM + (size_t)G * 5) * sizeof(float), stream);

    node_proj_kernel<<<(N + 255) / 256, 256, 0, stream>>>(node_attr, w_mpl, b_mpl, ps, pd, N);
    edge_kernel<<<2048, 256, 0, stream>>>(ei, edge_attr, w_mpl, ps, pd, xacc, E);
    node_mlp_kernel<<<(N + 255) / 256, 256, 0, stream>>>(xacc, batch, w1, b1, w2, b2, gacc, N);
    graph_head_kernel<<<(G + 255) / 256, 256, 0, stream>>>(gacc, w3, b3, w4, b4, out, G);
}

// Round 2
// 861.010 us; speedup vs baseline: 2.0712x; 2.0712x over previous
//
#include <hip/hip_runtime.h>

#define DN 5
#define DE 4
#define DM 10
#define NB_SCAT 1024          // scatter/hist blocks
#define BKT_SH 8              // bucket = dst >> 8  (256 nodes / bucket)
#define BKT_NODES 256
#define MAXBKT 1024           // LDS hist capacity (NBK=782 for N=200k)

// ---------------------------------------------------------------------------
// k1: per-node projections (padded rows of 16 floats for aligned gathers)
//     ps[n][0..9] = node_attr[n] @ W[0:5,:] + b ;  pd[n][0..9] = node_attr[n] @ W[5:10,:]
// ---------------------------------------------------------------------------
__global__ __launch_bounds__(256) void node_proj_kernel(
    const float* __restrict__ node_attr,
    const float* __restrict__ w_mpl, const float* __restrict__ b_mpl,
    float* __restrict__ ps, float* __restrict__ pd, int N)
{
    __shared__ float sw[110];
    int t = threadIdx.x;
    if (t < 100)      sw[t] = w_mpl[t];
    else if (t < 110) sw[t] = b_mpl[t - 100];
    __syncthreads();

    int n = blockIdx.x * blockDim.x + t;
    if (n >= N) return;

    float a[DN];
#pragma unroll
    for (int k = 0; k < DN; ++k) a[k] = node_attr[(size_t)n * DN + k];

    float vs[DM], vd[DM];
#pragma unroll
    for (int j = 0; j < DM; ++j) { vs[j] = sw[100 + j]; vd[j] = 0.f; }
#pragma unroll
    for (int k = 0; k < DN; ++k)
#pragma unroll
        for (int j = 0; j < DM; ++j) {
            vs[j] = fmaf(a[k], sw[k * DM + j],        vs[j]);
            vd[j] = fmaf(a[k], sw[(DN + k) * DM + j], vd[j]);
        }

    float* pr = ps + (size_t)n * 16;
    float* qr = pd + (size_t)n * 16;
    *reinterpret_cast<float4*>(pr)     = make_float4(vs[0], vs[1], vs[2], vs[3]);
    *reinterpret_cast<float4*>(pr + 4) = make_float4(vs[4], vs[5], vs[6], vs[7]);
    *reinterpret_cast<float2*>(pr + 8) = make_float2(vs[8], vs[9]);
    *reinterpret_cast<float4*>(qr)     = make_float4(vd[0], vd[1], vd[2], vd[3]);
    *reinterpret_cast<float4*>(qr + 4) = make_float4(vd[4], vd[5], vd[6], vd[7]);
    *reinterpret_cast<float2*>(qr + 8) = make_float2(vd[8], vd[9]);
}

// ---------------------------------------------------------------------------
// S1: per-block bucket histogram (LDS atomics only), cnt layout [bucket][block]
// ---------------------------------------------------------------------------
__global__ __launch_bounds__(256) void hist_kernel(
    const int* __restrict__ ei, unsigned* __restrict__ cnt,
    int E, int chunk, int nbk)
{
    __shared__ unsigned hist[MAXBKT];
    int t = threadIdx.x, b = blockIdx.x;
    for (int j = t; j < nbk; j += 256) hist[j] = 0;
    __syncthreads();

    int e0 = b * chunk, e1 = min(E, e0 + chunk);
    for (int i = e0 + t; i < e1; i += 256) {
        int d = ei[(size_t)E + i];
        atomicAdd(&hist[d >> BKT_SH], 1u);
    }
    __syncthreads();
    for (int j = t; j < nbk; j += 256)
        cnt[(size_t)j * NB_SCAT + b] = hist[j];
}

// ---------------------------------------------------------------------------
// scan1/scan2/scan3: flat exclusive scan of cnt[len], len = nbk*NB_SCAT
// ---------------------------------------------------------------------------
__global__ __launch_bounds__(256) void scan1_kernel(
    unsigned* __restrict__ cnt, unsigned* __restrict__ bsum, int len)
{
    __shared__ unsigned lds[256];
    int t = threadIdx.x;
    int i = blockIdx.x * 256 + t;
    unsigned v = (i < len) ? cnt[i] : 0u;
    lds[t] = v; __syncthreads();
#pragma unroll
    for (int o = 1; o < 256; o <<= 1) {
        unsigned add = (t >= o) ? lds[t - o] : 0u;
        __syncthreads();
        lds[t] += add;
        __syncthreads();
    }
    unsigned incl = lds[t];
    if (i < len) cnt[i] = incl - v;
    if (t == 255) bsum[blockIdx.x] = incl;
}

__global__ __launch_bounds__(1024) void scan2_kernel(unsigned* __restrict__ bsum, int nsb)
{
    __shared__ unsigned lds[1024];
    int t = threadIdx.x;
    int base = t * 4;
    unsigned v0 = (base + 0 < nsb) ? bsum[base + 0] : 0u;
    unsigned v1 = (base + 1 < nsb) ? bsum[base + 1] : 0u;
    unsigned v2 = (base + 2 < nsb) ? bsum[base + 2] : 0u;
    unsigned v3 = (base + 3 < nsb) ? bsum[base + 3] : 0u;
    unsigned tot = v0 + v1 + v2 + v3;
    lds[t] = tot; __syncthreads();
#pragma unroll
    for (int o = 1; o < 1024; o <<= 1) {
        unsigned add = (t >= o) ? lds[t - o] : 0u;
        __syncthreads();
        lds[t] += add;
        __syncthreads();
    }
    unsigned run = lds[t] - tot;
    if (base + 0 < nsb) bsum[base + 0] = run; run += v0;
    if (base + 1 < nsb) bsum[base + 1] = run; run += v1;
    if (base + 2 < nsb) bsum[base + 2] = run; run += v2;
    if (base + 3 < nsb) bsum[base + 3] = run;
}

__global__ __launch_bounds__(256) void scan3_kernel(
    unsigned* __restrict__ cnt, const unsigned* __restrict__ bsum, int len)
{
    int i = blockIdx.x * 256 + threadIdx.x;
    if (i < len) cnt[i] += bsum[i >> 8];
}

// ---------------------------------------------------------------------------
// S4: scatter edges to bucket-sorted records (LDS offset counters only)
//     rec_meta = src | (dst&255)<<18 ; rec_ea = edge_attr row
// ---------------------------------------------------------------------------
__global__ __launch_bounds__(256) void scatter_kernel(
    const int* __restrict__ ei, const float* __restrict__ edge_attr,
    const unsigned* __restrict__ cnt,
    unsigned* __restrict__ rec_meta, float4* __restrict__ rec_ea,
    int E, int chunk, int nbk)
{
    __shared__ unsigned woff[MAXBKT];
    int t = threadIdx.x, b = blockIdx.x;
    for (int j = t; j < nbk; j += 256) woff[j] = cnt[(size_t)j * NB_SCAT + b];
    __syncthreads();

    int e0 = b * chunk, e1 = min(E, e0 + chunk);
    for (int i = e0 + t; i < e1; i += 256) {
        int s = ei[i];
        int d = ei[(size_t)E + i];
        float4 ea = reinterpret_cast<const float4*>(edge_attr)[i];
        unsigned p = atomicAdd(&woff[d >> BKT_SH], 1u);
        rec_meta[p] = (unsigned)s | ((unsigned)(d & 255) << 18);
        rec_ea[p] = ea;
    }
}

// ---------------------------------------------------------------------------
// G: per-bucket gather. LDS accumulator (256 nodes x 10), LDS f32 atomics.
//    Fused node-MLP head + wave-segmented pooling into gacc.
// ---------------------------------------------------------------------------
__global__ __launch_bounds__(256) void gather_kernel(
    const unsigned* __restrict__ rec_meta, const float4* __restrict__ rec_ea,
    const unsigned* __restrict__ cnt,
    const float* __restrict__ ps, const float* __restrict__ pd,
    const float* __restrict__ w_mpl,
    const float* __restrict__ w1, const float* __restrict__ b1,
    const float* __restrict__ w2, const float* __restrict__ b2,
    const int* __restrict__ batch,
    float* __restrict__ gacc, int E, int N, int nbk)
{
    __shared__ float acc[BKT_NODES * DM];     // 10 KB
    __shared__ float pdl[BKT_NODES * DM];     // 10 KB
    __shared__ float swe[DE * DM];            // We
    __shared__ float s1[100], sb1[10], s2[50], sb2[5];

    int t = threadIdx.x, j = blockIdx.x;
    int nb0 = j * BKT_NODES;

    // zero accumulator + stage pd tile
    for (int i = t; i < BKT_NODES * DM; i += 256) {
        acc[i] = 0.f;
        int r = i / DM, c = i - r * DM;
        pdl[i] = (nb0 + r < N) ? pd[(size_t)(nb0 + r) * 16 + c] : 0.f;
    }
    if (t < 40)            swe[t] = w_mpl[(2 * DN) * DM + t];
    else if (t < 140)      s1[t - 40] = w1[t - 40];
    else if (t < 150)      sb1[t - 140] = b1[t - 140];
    else if (t < 200)      s2[t - 150] = w2[t - 150];
    else if (t < 205)      sb2[t - 200] = b2[t - 200];
    __syncthreads();

    float we[DE][DM];
#pragma unroll
    for (int k = 0; k < DE; ++k)
#pragma unroll
        for (int q = 0; q < DM; ++q) we[k][q] = swe[k * DM + q];

    unsigned start = cnt[(size_t)j * NB_SCAT];
    unsigned end   = (j + 1 < nbk) ? cnt[(size_t)(j + 1) * NB_SCAT] : (unsigned)E;

    for (unsigned i = start + t; i < end; i += 256) {
        unsigned meta = rec_meta[i];
        int s  = meta & 0x3FFFF;
        int dl = meta >> 18;
        float4 ea = rec_ea[i];

        const float* pr = ps + (size_t)s * 16;
        float4 a0 = *reinterpret_cast<const float4*>(pr);
        float4 a1 = *reinterpret_cast<const float4*>(pr + 4);
        float2 a2 = *reinterpret_cast<const float2*>(pr + 8);
        float psv[DM] = {a0.x, a0.y, a0.z, a0.w, a1.x, a1.y, a1.z, a1.w, a2.x, a2.y};

#pragma unroll
        for (int q = 0; q < DM; ++q) {
            float v = psv[q] + pdl[dl * DM + q];
            v = fmaf(ea.x, we[0][q], v);
            v = fmaf(ea.y, we[1][q], v);
            v = fmaf(ea.z, we[2][q], v);
            v = fmaf(ea.w, we[3][q], v);
            v = fmaxf(v, 0.f);
            atomicAdd(&acc[dl * DM + q], v);   // LDS f32 atomic (ds_add_f32)
        }
    }
    __syncthreads();

    // fused node-MLP head + segmented pooling
    int n = nb0 + t;
    bool valid = (n < N);
    int g = 0x7fffffff;
    float h2[5] = {0.f, 0.f, 0.f, 0.f, 0.f};
    if (valid) {
        float x[DM];
#pragma unroll
        for (int k = 0; k < DM; ++k) x[k] = acc[t * DM + k];
        float h1[10];
#pragma unroll
        for (int q = 0; q < 10; ++q) h1[q] = sb1[q];
#pragma unroll
        for (int k = 0; k < 10; ++k)
#pragma unroll
            for (int q = 0; q < 10; ++q) h1[q] = fmaf(x[k], s1[k * 10 + q], h1[q]);
#pragma unroll
        for (int q = 0; q < 10; ++q) h1[q] = fmaxf(h1[q], 0.f);
#pragma unroll
        for (int q = 0; q < 5; ++q) h2[q] = sb2[q];
#pragma unroll
        for (int k = 0; k < 10; ++k)
#pragma unroll
            for (int q = 0; q < 5; ++q) h2[q] = fmaf(h1[k], s2[k * 5 + q], h2[q]);
#pragma unroll
        for (int q = 0; q < 5; ++q) h2[q] = fmaxf(h2[q], 0.f);
        g = batch[n];
    }

    // wave-segmented suffix reduction (batch sorted => g monotone over lanes)
    int lane = t & 63;
#pragma unroll
    for (int o = 1; o < 64; o <<= 1) {
        int go = __shfl_down(g, o);
        float v0 = __shfl_down(h2[0], o);
        float v1 = __shfl_down(h2[1], o);
        float v2 = __shfl_down(h2[2], o);
        float v3 = __shfl_down(h2[3], o);
        float v4 = __shfl_down(h2[4], o);
        if (lane + o < 64 && go == g) {
            h2[0] += v0; h2[1] += v1; h2[2] += v2; h2[3] += v3; h2[4] += v4;
        }
    }
    int gp = __shfl_up(g, 1);
    bool head = (lane == 0) || (gp != g);
    if (head && g != 0x7fffffff) {
#pragma unroll
        for (int q = 0; q < 5; ++q)
            if (h2[q] != 0.f) unsafeAtomicAdd(&gacc[(size_t)g * 5 + q], h2[q]);
    }
}

// ---------------------------------------------------------------------------
// k4: per-graph head
// ---------------------------------------------------------------------------
__global__ __launch_bounds__(256) void graph_head_kernel(
    const float* __restrict__ gacc,
    const float* __restrict__ w3, const float* __restrict__ b3,
    const float* __restrict__ w4, const float* __restrict__ b4,
    float* __restrict__ out, int G)
{
    __shared__ float s3[25], sb3[5], s4[5], sb4[1];
    int t = threadIdx.x;
    if (t < 25)       s3[t] = w3[t];
    else if (t < 30)  sb3[t - 25] = b3[t - 25];
    else if (t < 35)  s4[t - 30] = w4[t - 30];
    else if (t == 35) sb4[0] = b4[0];
    __syncthreads();

    int g = blockIdx.x * blockDim.x + t;
    if (g >= G) return;

    float x[5];
#pragma unroll
    for (int k = 0; k < 5; ++k) x[k] = gacc[(size_t)g * 5 + k];

    float o = sb4[0];
#pragma unroll
    for (int q = 0; q < 5; ++q) {
        float h = sb3[q];
#pragma unroll
        for (int k = 0; k < 5; ++k) h = fmaf(x[k], s3[k * 5 + q], h);
        h = fmaxf(h, 0.f);
        o = fmaf(h, s4[q], o);
    }
    out[g] = o;
}

// ---------------------------------------------------------------------------
extern "C" void kernel_launch(void* const* d_in, const int* in_sizes, int n_in,
                              void* d_out, int out_size, void* d_ws, size_t ws_size,
                              hipStream_t stream)
{
    const int*   ei        = (const int*)d_in[0];
    const float* node_attr = (const float*)d_in[1];
    const float* edge_attr = (const float*)d_in[2];
    const int*   batch     = (const int*)d_in[3];
    const float* w_mpl = (const float*)d_in[5];
    const float* b_mpl = (const float*)d_in[6];
    const float* w1    = (const float*)d_in[7];
    const float* b1    = (const float*)d_in[8];
    const float* w2    = (const float*)d_in[9];
    const float* b2    = (const float*)d_in[10];
    const float* w3    = (const float*)d_in[11];
    const float* b3    = (const float*)d_in[12];
    const float* w4    = (const float*)d_in[13];
    const float* b4    = (const float*)d_in[14];
    float* out = (float*)d_out;

    const int E = in_sizes[0] / 2;
    const int N = in_sizes[1] / DN;
    const int G = out_size;

    const int nbk   = (N + BKT_NODES - 1) / BKT_NODES;     // 782
    const int chunk = (E + NB_SCAT - 1) / NB_SCAT;         // 6250
    const int len   = nbk * NB_SCAT;                       // 800768
    const int nsb   = (len + 255) / 256;                   // 3128 (<=4096)

    // workspace layout
    char* p = (char*)d_ws;
    float4*   rec_ea   = (float4*)p;   p += (size_t)E * 16;
    float*    ps       = (float*)p;    p += (size_t)N * 16 * 4;
    float*    pd       = (float*)p;    p += (size_t)N * 16 * 4;
    unsigned* rec_meta = (unsigned*)p; p += (size_t)E * 4;
    unsigned* cnt      = (unsigned*)p; p += (size_t)len * 4;
    unsigned* bsum     = (unsigned*)p; p += (size_t)nsb * 4;
    float*    gacc     = (float*)p;    p += (size_t)G * 5 * 4;

    hipMemsetAsync(gacc, 0, (size_t)G * 5 * 4, stream);

    node_proj_kernel<<<(N + 255) / 256, 256, 0, stream>>>(node_attr, w_mpl, b_mpl, ps, pd, N);
    hist_kernel<<<NB_SCAT, 256, 0, stream>>>(ei, cnt, E, chunk, nbk);
    scan1_kernel<<<nsb, 256, 0, stream>>>(cnt, bsum, len);
    scan2_kernel<<<1, 1024, 0, stream>>>(bsum, nsb);
    scan3_kernel<<<nsb, 256, 0, stream>>>(cnt, bsum, len);
    scatter_kernel<<<NB_SCAT, 256, 0, stream>>>(ei, edge_attr, cnt, rec_meta, rec_ea, E, chunk, nbk);
    gather_kernel<<<nbk, 256, 0, stream>>>(rec_meta, rec_ea, cnt, ps, pd, w_mpl,
                                           w1, b1, w2, b2, batch, gacc, E, N, nbk);
    graph_head_kernel<<<(G + 255) / 256, 256, 0, stream>>>(gacc, w3, b3, w4, b4, out, G);
}

// Round 3
// 787.805 us; speedup vs baseline: 2.2637x; 1.0929x over previous
//
#include <hip/hip_runtime.h>

#define DN 5
#define DE 4
#define DM 10
#define NB_SCAT 512           // scatter/hist blocks
#define BKT_SH 8              // bucket = dst >> 8  (256 nodes / bucket)
#define BKT_NODES 256
#define MAXBKT 1024           // LDS hist capacity (NBK=782 for N=200k)

// ---------------------------------------------------------------------------
// k1: per-node projections (padded rows of 16 floats for aligned gathers)
//     ps[n][0..9] = node_attr[n] @ W[0:5,:] + b ;  pd[n][0..9] = node_attr[n] @ W[5:10,:]
// ---------------------------------------------------------------------------
__global__ __launch_bounds__(256) void node_proj_kernel(
    const float* __restrict__ node_attr,
    const float* __restrict__ w_mpl, const float* __restrict__ b_mpl,
    float* __restrict__ ps, float* __restrict__ pd, int N)
{
    __shared__ float sw[110];
    int t = threadIdx.x;
    if (t < 100)      sw[t] = w_mpl[t];
    else if (t < 110) sw[t] = b_mpl[t - 100];
    __syncthreads();

    int n = blockIdx.x * blockDim.x + t;
    if (n >= N) return;

    float a[DN];
#pragma unroll
    for (int k = 0; k < DN; ++k) a[k] = node_attr[(size_t)n * DN + k];

    float vs[DM], vd[DM];
#pragma unroll
    for (int j = 0; j < DM; ++j) { vs[j] = sw[100 + j]; vd[j] = 0.f; }
#pragma unroll
    for (int k = 0; k < DN; ++k)
#pragma unroll
        for (int j = 0; j < DM; ++j) {
            vs[j] = fmaf(a[k], sw[k * DM + j],        vs[j]);
            vd[j] = fmaf(a[k], sw[(DN + k) * DM + j], vd[j]);
        }

    float* pr = ps + (size_t)n * 16;
    float* qr = pd + (size_t)n * 16;
    *reinterpret_cast<float4*>(pr)     = make_float4(vs[0], vs[1], vs[2], vs[3]);
    *reinterpret_cast<float4*>(pr + 4) = make_float4(vs[4], vs[5], vs[6], vs[7]);
    *reinterpret_cast<float2*>(pr + 8) = make_float2(vs[8], vs[9]);
    *reinterpret_cast<float4*>(qr)     = make_float4(vd[0], vd[1], vd[2], vd[3]);
    *reinterpret_cast<float4*>(qr + 4) = make_float4(vd[4], vd[5], vd[6], vd[7]);
    *reinterpret_cast<float2*>(qr + 8) = make_float2(vd[8], vd[9]);
}

// ---------------------------------------------------------------------------
// S1: per-block bucket histogram (LDS atomics only), cnt layout [bucket][block]
// ---------------------------------------------------------------------------
__global__ __launch_bounds__(256) void hist_kernel(
    const int* __restrict__ ei, unsigned* __restrict__ cnt,
    int E, int chunk, int nbk)
{
    __shared__ unsigned hist[MAXBKT];
    int t = threadIdx.x, b = blockIdx.x;
    for (int j = t; j < nbk; j += 256) hist[j] = 0;
    __syncthreads();

    int e0 = b * chunk, e1 = min(E, e0 + chunk);
    for (int i = e0 + t; i < e1; i += 256) {
        int d = ei[(size_t)E + i];
        atomicAdd(&hist[d >> BKT_SH], 1u);
    }
    __syncthreads();
    for (int j = t; j < nbk; j += 256)
        cnt[(size_t)j * NB_SCAT + b] = hist[j];
}

// ---------------------------------------------------------------------------
// scan1/scan2/scan3: flat exclusive scan of cnt[len], len = nbk*NB_SCAT
// ---------------------------------------------------------------------------
__global__ __launch_bounds__(256) void scan1_kernel(
    unsigned* __restrict__ cnt, unsigned* __restrict__ bsum, int len)
{
    __shared__ unsigned lds[256];
    int t = threadIdx.x;
    int i = blockIdx.x * 256 + t;
    unsigned v = (i < len) ? cnt[i] : 0u;
    lds[t] = v; __syncthreads();
#pragma unroll
    for (int o = 1; o < 256; o <<= 1) {
        unsigned add = (t >= o) ? lds[t - o] : 0u;
        __syncthreads();
        lds[t] += add;
        __syncthreads();
    }
    unsigned incl = lds[t];
    if (i < len) cnt[i] = incl - v;
    if (t == 255) bsum[blockIdx.x] = incl;
}

__global__ __launch_bounds__(1024) void scan2_kernel(unsigned* __restrict__ bsum, int nsb)
{
    __shared__ unsigned lds[1024];
    int t = threadIdx.x;
    int base = t * 4;
    unsigned v0 = (base + 0 < nsb) ? bsum[base + 0] : 0u;
    unsigned v1 = (base + 1 < nsb) ? bsum[base + 1] : 0u;
    unsigned v2 = (base + 2 < nsb) ? bsum[base + 2] : 0u;
    unsigned v3 = (base + 3 < nsb) ? bsum[base + 3] : 0u;
    unsigned tot = v0 + v1 + v2 + v3;
    lds[t] = tot; __syncthreads();
#pragma unroll
    for (int o = 1; o < 1024; o <<= 1) {
        unsigned add = (t >= o) ? lds[t - o] : 0u;
        __syncthreads();
        lds[t] += add;
        __syncthreads();
    }
    unsigned run = lds[t] - tot;
    if (base + 0 < nsb) bsum[base + 0] = run; run += v0;
    if (base + 1 < nsb) bsum[base + 1] = run; run += v1;
    if (base + 2 < nsb) bsum[base + 2] = run; run += v2;
    if (base + 3 < nsb) bsum[base + 3] = run;
}

__global__ __launch_bounds__(256) void scan3_kernel(
    unsigned* __restrict__ cnt, const unsigned* __restrict__ bsum, int len)
{
    int i = blockIdx.x * 256 + threadIdx.x;
    if (i < len) cnt[i] += bsum[i >> 8];
}

// ---------------------------------------------------------------------------
// S4: scatter edges to bucket-sorted records (LDS offset counters only)
//     rec_meta = src | (dst&255)<<18 ; rec_ea = edge_attr row
// ---------------------------------------------------------------------------
__global__ __launch_bounds__(256) void scatter_kernel(
    const int* __restrict__ ei, const float* __restrict__ edge_attr,
    const unsigned* __restrict__ cnt,
    unsigned* __restrict__ rec_meta, float4* __restrict__ rec_ea,
    int E, int chunk, int nbk)
{
    __shared__ unsigned woff[MAXBKT];
    int t = threadIdx.x, b = blockIdx.x;
    for (int j = t; j < nbk; j += 256) woff[j] = cnt[(size_t)j * NB_SCAT + b];
    __syncthreads();

    int e0 = b * chunk, e1 = min(E, e0 + chunk);
    for (int i = e0 + t; i < e1; i += 256) {
        int s = ei[i];
        int d = ei[(size_t)E + i];
        float4 ea = reinterpret_cast<const float4*>(edge_attr)[i];
        unsigned p = atomicAdd(&woff[d >> BKT_SH], 1u);
        rec_meta[p] = (unsigned)s | ((unsigned)(d & 255) << 18);
        rec_ea[p] = ea;
    }
}

// ---------------------------------------------------------------------------
// G: per-(bucket,split) gather. LDS accumulator (256 nodes x 10), LDS f32
//    atomics; writes contiguous partial tile to xpart[split].
// ---------------------------------------------------------------------------
__global__ __launch_bounds__(256) void gather_kernel(
    const unsigned* __restrict__ rec_meta, const float4* __restrict__ rec_ea,
    const unsigned* __restrict__ cnt,
    const float* __restrict__ ps, const float* __restrict__ pd,
    const float* __restrict__ w_mpl,
    float* __restrict__ xpart, size_t xstride,
    int E, int N, int nbk, int nsplit)
{
    __shared__ float acc[BKT_NODES * DM];     // 10 KB
    __shared__ float pdl[BKT_NODES * DM];     // 10 KB
    __shared__ float swe[DE * DM];            // We

    int t = threadIdx.x;
    int j = blockIdx.x / nsplit;              // bucket
    int sp = blockIdx.x - j * nsplit;         // split
    int nb0 = j * BKT_NODES;

    for (int i = t; i < BKT_NODES * DM; i += 256) {
        acc[i] = 0.f;
        int r = i / DM, c = i - r * DM;
        pdl[i] = (nb0 + r < N) ? pd[(size_t)(nb0 + r) * 16 + c] : 0.f;
    }
    if (t < 40) swe[t] = w_mpl[(2 * DN) * DM + t];
    __syncthreads();

    float we[DE][DM];
#pragma unroll
    for (int k = 0; k < DE; ++k)
#pragma unroll
        for (int q = 0; q < DM; ++q) we[k][q] = swe[k * DM + q];

    unsigned start = cnt[(size_t)j * NB_SCAT];
    unsigned end   = (j + 1 < nbk) ? cnt[(size_t)(j + 1) * NB_SCAT] : (unsigned)E;
    unsigned blen  = end - start;
    unsigned csz   = (blen + nsplit - 1) / nsplit;
    unsigned ss    = start + (unsigned)sp * csz;
    unsigned se    = min(end, ss + csz);

    for (unsigned i = ss + t; i < se; i += 256) {
        unsigned meta = rec_meta[i];
        int s  = meta & 0x3FFFF;
        int dl = meta >> 18;
        float4 ea = rec_ea[i];

        const float* pr = ps + (size_t)s * 16;
        float4 a0 = *reinterpret_cast<const float4*>(pr);
        float4 a1 = *reinterpret_cast<const float4*>(pr + 4);
        float2 a2 = *reinterpret_cast<const float2*>(pr + 8);
        float psv[DM] = {a0.x, a0.y, a0.z, a0.w, a1.x, a1.y, a1.z, a1.w, a2.x, a2.y};

#pragma unroll
        for (int q = 0; q < DM; ++q) {
            float v = psv[q] + pdl[dl * DM + q];
            v = fmaf(ea.x, we[0][q], v);
            v = fmaf(ea.y, we[1][q], v);
            v = fmaf(ea.z, we[2][q], v);
            v = fmaf(ea.w, we[3][q], v);
            v = fmaxf(v, 0.f);
            atomicAdd(&acc[dl * DM + q], v);   // LDS f32 atomic (ds_add_f32)
        }
    }
    __syncthreads();

    // contiguous 10 KB partial write (coalesced)
    float* dst = xpart + (size_t)sp * xstride + (size_t)nb0 * DM;
    for (int i = t; i < BKT_NODES * DM; i += 256) dst[i] = acc[i];
}

// ---------------------------------------------------------------------------
// C: combine partials + node-MLP head + wave-segmented pooling into gacc
// ---------------------------------------------------------------------------
__global__ __launch_bounds__(256) void combine_kernel(
    const float* __restrict__ xpart, size_t xstride,
    const int* __restrict__ batch,
    const float* __restrict__ w1, const float* __restrict__ b1,
    const float* __restrict__ w2, const float* __restrict__ b2,
    float* __restrict__ gacc, int N, int nsplit)
{
    __shared__ float s1[100], sb1[10], s2[50], sb2[5];
    int t = threadIdx.x;
    if (t < 100)      s1[t] = w1[t];
    else if (t < 110) sb1[t - 100] = b1[t - 100];
    else if (t < 160) s2[t - 110] = w2[t - 110];
    else if (t < 165) sb2[t - 160] = b2[t - 160];
    __syncthreads();

    int n = blockIdx.x * blockDim.x + t;
    bool valid = (n < N);
    int g = 0x7fffffff;
    float h2[5] = {0.f, 0.f, 0.f, 0.f, 0.f};

    if (valid) {
        float x[DM];
#pragma unroll
        for (int q = 0; q < DM; ++q) x[q] = 0.f;
        for (int sp = 0; sp < nsplit; ++sp) {
            const float2* row = reinterpret_cast<const float2*>(
                xpart + (size_t)sp * xstride + (size_t)n * DM);
#pragma unroll
            for (int h = 0; h < 5; ++h) {
                float2 v = row[h];
                x[2 * h] += v.x; x[2 * h + 1] += v.y;
            }
        }

        float h1[10];
#pragma unroll
        for (int q = 0; q < 10; ++q) h1[q] = sb1[q];
#pragma unroll
        for (int k = 0; k < 10; ++k)
#pragma unroll
            for (int q = 0; q < 10; ++q) h1[q] = fmaf(x[k], s1[k * 10 + q], h1[q]);
#pragma unroll
        for (int q = 0; q < 10; ++q) h1[q] = fmaxf(h1[q], 0.f);
#pragma unroll
        for (int q = 0; q < 5; ++q) h2[q] = sb2[q];
#pragma unroll
        for (int k = 0; k < 10; ++k)
#pragma unroll
            for (int q = 0; q < 5; ++q) h2[q] = fmaf(h1[k], s2[k * 5 + q], h2[q]);
#pragma unroll
        for (int q = 0; q < 5; ++q) h2[q] = fmaxf(h2[q], 0.f);
        g = batch[n];
    }

    // wave-segmented suffix reduction (batch sorted => g monotone over lanes)
    int lane = t & 63;
#pragma unroll
    for (int o = 1; o < 64; o <<= 1) {
        int go = __shfl_down(g, o);
        float v0 = __shfl_down(h2[0], o);
        float v1 = __shfl_down(h2[1], o);
        float v2 = __shfl_down(h2[2], o);
        float v3 = __shfl_down(h2[3], o);
        float v4 = __shfl_down(h2[4], o);
        if (lane + o < 64 && go == g) {
            h2[0] += v0; h2[1] += v1; h2[2] += v2; h2[3] += v3; h2[4] += v4;
        }
    }
    int gp = __shfl_up(g, 1);
    bool head = (lane == 0) || (gp != g);
    if (head && g != 0x7fffffff) {
#pragma unroll
        for (int q = 0; q < 5; ++q)
            if (h2[q] != 0.f) unsafeAtomicAdd(&gacc[(size_t)g * 5 + q], h2[q]);
    }
}

// ---------------------------------------------------------------------------
// k4: per-graph head
// ---------------------------------------------------------------------------
__global__ __launch_bounds__(256) void graph_head_kernel(
    const float* __restrict__ gacc,
    const float* __restrict__ w3, const float* __restrict__ b3,
    const float* __restrict__ w4, const float* __restrict__ b4,
    float* __restrict__ out, int G)
{
    __shared__ float s3[25], sb3[5], s4[5], sb4[1];
    int t = threadIdx.x;
    if (t < 25)       s3[t] = w3[t];
    else if (t < 30)  sb3[t - 25] = b3[t - 25];
    else if (t < 35)  s4[t - 30] = w4[t - 30];
    else if (t == 35) sb4[0] = b4[0];
    __syncthreads();

    int g = blockIdx.x * blockDim.x + t;
    if (g >= G) return;

    float x[5];
#pragma unroll
    for (int k = 0; k < 5; ++k) x[k] = gacc[(size_t)g * 5 + k];

    float o = sb4[0];
#pragma unroll
    for (int q = 0; q < 5; ++q) {
        float h = sb3[q];
#pragma unroll
        for (int k = 0; k < 5; ++k) h = fmaf(x[k], s3[k * 5 + q], h);
        h = fmaxf(h, 0.f);
        o = fmaf(h, s4[q], o);
    }
    out[g] = o;
}

// ---------------------------------------------------------------------------
extern "C" void kernel_launch(void* const* d_in, const int* in_sizes, int n_in,
                              void* d_out, int out_size, void* d_ws, size_t ws_size,
                              hipStream_t stream)
{
    const int*   ei        = (const int*)d_in[0];
    const float* node_attr = (const float*)d_in[1];
    const float* edge_attr = (const float*)d_in[2];
    const int*   batch     = (const int*)d_in[3];
    const float* w_mpl = (const float*)d_in[5];
    const float* b_mpl = (const float*)d_in[6];
    const float* w1    = (const float*)d_in[7];
    const float* b1    = (const float*)d_in[8];
    const float* w2    = (const float*)d_in[9];
    const float* b2    = (const float*)d_in[10];
    const float* w3    = (const float*)d_in[11];
    const float* b3    = (const float*)d_in[12];
    const float* w4    = (const float*)d_in[13];
    const float* b4    = (const float*)d_in[14];
    float* out = (float*)d_out;

    const int E = in_sizes[0] / 2;
    const int N = in_sizes[1] / DN;
    const int G = out_size;

    const int nbk   = (N + BKT_NODES - 1) / BKT_NODES;     // 782
    const int chunk = (E + NB_SCAT - 1) / NB_SCAT;         // 12500
    const int len   = nbk * NB_SCAT;                       // 400384
    const int nsb   = (len + 255) / 256;                   // 1564 (<=4096)

    // workspace layout
    char* p = (char*)d_ws;
    float4*   rec_ea   = (float4*)p;   p += (size_t)E * 16;
    float*    ps       = (float*)p;    p += (size_t)N * 16 * 4;
    float*    pd       = (float*)p;    p += (size_t)N * 16 * 4;
    unsigned* rec_meta = (unsigned*)p; p += (size_t)E * 4;
    unsigned* cnt      = (unsigned*)p; p += (size_t)len * 4;
    unsigned* bsum     = (unsigned*)p; p += (size_t)((nsb + 3) & ~3) * 4;
    float*    gacc     = (float*)p;    p += (size_t)G * 5 * 4;
    float*    xpart    = (float*)p;

    // pick nsplit per available workspace (deterministic in ws_size)
    size_t used = (size_t)(p - (char*)d_ws);
    size_t xstride = (size_t)nbk * BKT_NODES * DM;         // floats per split
    int nsplit = 4;
    while (nsplit > 1 && used + (size_t)nsplit * xstride * 4 > ws_size) nsplit >>= 1;

    hipMemsetAsync(gacc, 0, (size_t)G * 5 * 4, stream);

    node_proj_kernel<<<(N + 255) / 256, 256, 0, stream>>>(node_attr, w_mpl, b_mpl, ps, pd, N);
    hist_kernel<<<NB_SCAT, 256, 0, stream>>>(ei, cnt, E, chunk, nbk);
    scan1_kernel<<<nsb, 256, 0, stream>>>(cnt, bsum, len);
    scan2_kernel<<<1, 1024, 0, stream>>>(bsum, nsb);
    scan3_kernel<<<nsb, 256, 0, stream>>>(cnt, bsum, len);
    scatter_kernel<<<NB_SCAT, 256, 0, stream>>>(ei, edge_attr, cnt, rec_meta, rec_ea, E, chunk, nbk);
    gather_kernel<<<nbk * nsplit, 256, 0, stream>>>(rec_meta, rec_ea, cnt, ps, pd, w_mpl,
                                                    xpart, xstride, E, N, nbk, nsplit);
    combine_kernel<<<nbk, 256, 0, stream>>>(xpart, xstride, batch, w1, b1, w2, b2, gacc, N, nsplit);
    graph_head_kernel<<<(G + 255) / 256, 256, 0, stream>>>(gacc, w3, b3, w4, b4, out, G);
}

// Round 4
// 621.743 us; speedup vs baseline: 2.8683x; 1.2671x over previous
//
#include <hip/hip_runtime.h>

#define DN 5
#define DE 4
#define DM 10
#define NB_SCAT 512           // scatter/hist blocks
#define BKT_SH 8              // bucket = dst >> 8  (256 nodes / bucket)
#define BKT_NODES 256
#define MAXBKT 1024           // LDS hist capacity (NBK=782 for N=200k)

// ---------------------------------------------------------------------------
// P: pack node_attr rows into aligned 32B records (float4 x2)
// ---------------------------------------------------------------------------
__global__ __launch_bounds__(256) void pack_kernel(
    const float* __restrict__ node_attr, float4* __restrict__ napack, int N)
{
    int n = blockIdx.x * 256 + threadIdx.x;
    if (n >= N) return;
    const float* r = node_attr + (size_t)n * DN;
    napack[2 * (size_t)n]     = make_float4(r[0], r[1], r[2], r[3]);
    napack[2 * (size_t)n + 1] = make_float4(r[4], 0.f, 0.f, 0.f);
}

// ---------------------------------------------------------------------------
// S1: per-block bucket histogram (LDS atomics only), cnt layout [bucket][block]
// ---------------------------------------------------------------------------
__global__ __launch_bounds__(256) void hist_kernel(
    const int* __restrict__ ei, unsigned* __restrict__ cnt,
    int E, int chunk, int nbk)
{
    __shared__ unsigned hist[MAXBKT];
    int t = threadIdx.x, b = blockIdx.x;
    for (int j = t; j < nbk; j += 256) hist[j] = 0;
    __syncthreads();

    int e0 = b * chunk, e1 = min(E, e0 + chunk);
    for (int i = e0 + t; i < e1; i += 256) {
        int d = ei[(size_t)E + i];
        atomicAdd(&hist[d >> BKT_SH], 1u);
    }
    __syncthreads();
    for (int j = t; j < nbk; j += 256)
        cnt[(size_t)j * NB_SCAT + b] = hist[j];
}

// ---------------------------------------------------------------------------
// scan1/scan2/scan3: flat exclusive scan of cnt[len], len = nbk*NB_SCAT
// ---------------------------------------------------------------------------
__global__ __launch_bounds__(256) void scan1_kernel(
    unsigned* __restrict__ cnt, unsigned* __restrict__ bsum, int len)
{
    __shared__ unsigned lds[256];
    int t = threadIdx.x;
    int i = blockIdx.x * 256 + t;
    unsigned v = (i < len) ? cnt[i] : 0u;
    lds[t] = v; __syncthreads();
#pragma unroll
    for (int o = 1; o < 256; o <<= 1) {
        unsigned add = (t >= o) ? lds[t - o] : 0u;
        __syncthreads();
        lds[t] += add;
        __syncthreads();
    }
    unsigned incl = lds[t];
    if (i < len) cnt[i] = incl - v;
    if (t == 255) bsum[blockIdx.x] = incl;
}

__global__ __launch_bounds__(1024) void scan2_kernel(unsigned* __restrict__ bsum, int nsb)
{
    __shared__ unsigned lds[1024];
    int t = threadIdx.x;
    int base = t * 4;
    unsigned v0 = (base + 0 < nsb) ? bsum[base + 0] : 0u;
    unsigned v1 = (base + 1 < nsb) ? bsum[base + 1] : 0u;
    unsigned v2 = (base + 2 < nsb) ? bsum[base + 2] : 0u;
    unsigned v3 = (base + 3 < nsb) ? bsum[base + 3] : 0u;
    unsigned tot = v0 + v1 + v2 + v3;
    lds[t] = tot; __syncthreads();
#pragma unroll
    for (int o = 1; o < 1024; o <<= 1) {
        unsigned add = (t >= o) ? lds[t - o] : 0u;
        __syncthreads();
        lds[t] += add;
        __syncthreads();
    }
    unsigned run = lds[t] - tot;
    if (base + 0 < nsb) bsum[base + 0] = run; run += v0;
    if (base + 1 < nsb) bsum[base + 1] = run; run += v1;
    if (base + 2 < nsb) bsum[base + 2] = run; run += v2;
    if (base + 3 < nsb) bsum[base + 3] = run;
}

__global__ __launch_bounds__(256) void scan3_kernel(
    unsigned* __restrict__ cnt, const unsigned* __restrict__ bsum, int len)
{
    int i = blockIdx.x * 256 + threadIdx.x;
    if (i < len) cnt[i] += bsum[i >> 8];
}

// ---------------------------------------------------------------------------
// S4: scatter edges to bucket-sorted records (LDS offset counters only)
//     rec_meta = src | (dst&255)<<18 ; rec_ea = edge_attr row
// ---------------------------------------------------------------------------
__global__ __launch_bounds__(256) void scatter_kernel(
    const int* __restrict__ ei, const float* __restrict__ edge_attr,
    const unsigned* __restrict__ cnt,
    unsigned* __restrict__ rec_meta, float4* __restrict__ rec_ea,
    int E, int chunk, int nbk)
{
    __shared__ unsigned woff[MAXBKT];
    int t = threadIdx.x, b = blockIdx.x;
    for (int j = t; j < nbk; j += 256) woff[j] = cnt[(size_t)j * NB_SCAT + b];
    __syncthreads();

    int e0 = b * chunk, e1 = min(E, e0 + chunk);
    for (int i = e0 + t; i < e1; i += 256) {
        int s = ei[i];
        int d = ei[(size_t)E + i];
        float4 ea = reinterpret_cast<const float4*>(edge_attr)[i];
        unsigned p = atomicAdd(&woff[d >> BKT_SH], 1u);
        rec_meta[p] = (unsigned)s | ((unsigned)(d & 255) << 18);
        rec_ea[p] = ea;
    }
}

// ---------------------------------------------------------------------------
// G: per-(bucket,split) gather. Gathers raw napack[src] (6.4 MB table),
//    computes BOTH projections in-kernel, accumulates via LDS f32 atomics,
//    writes contiguous partial tile.  4-edge software pipeline per thread.
// ---------------------------------------------------------------------------
__global__ __launch_bounds__(256) void gather_kernel(
    const unsigned* __restrict__ rec_meta, const float4* __restrict__ rec_ea,
    const unsigned* __restrict__ cnt,
    const float4* __restrict__ napack,
    const float* __restrict__ w_mpl, const float* __restrict__ b_mpl,
    float* __restrict__ xpart, size_t xstride,
    int E, int N, int nbk, int nsplit)
{
    __shared__ float acc[BKT_NODES * DM];      // 10 KB
    __shared__ float pdl[BKT_NODES * 12];      // 12 KB (48B rows, 16B aligned)
    __shared__ float sws[50];                  // W_src
    __shared__ float swe[40];                  // W_edge

    int t = threadIdx.x;
    int j  = blockIdx.x / nsplit;
    int sp = blockIdx.x - j * nsplit;
    int nb0 = j * BKT_NODES;

    if (t < 50)       sws[t] = w_mpl[t];
    else if (t < 90)  swe[t - 50] = w_mpl[100 + (t - 50)];

    for (int i = t; i < BKT_NODES * DM; i += 256) acc[i] = 0.f;

    // stage dst-projection tile (bias folded in): row per thread
    {
        int n = nb0 + t;
        float a0 = 0.f, a1 = 0.f, a2 = 0.f, a3 = 0.f, a4 = 0.f;
        if (n < N) {
            float4 r0 = napack[2 * (size_t)n];
            float4 r1 = napack[2 * (size_t)n + 1];
            a0 = r0.x; a1 = r0.y; a2 = r0.z; a3 = r0.w; a4 = r1.x;
        }
#pragma unroll
        for (int q = 0; q < DM; ++q) {
            float v = b_mpl[q];
            v = fmaf(a0, w_mpl[50 + q],      v);
            v = fmaf(a1, w_mpl[60 + q],      v);
            v = fmaf(a2, w_mpl[70 + q],      v);
            v = fmaf(a3, w_mpl[80 + q],      v);
            v = fmaf(a4, w_mpl[90 + q],      v);
            pdl[t * 12 + q] = v;
        }
    }
    __syncthreads();

    unsigned start = cnt[(size_t)j * NB_SCAT];
    unsigned end   = (j + 1 < nbk) ? cnt[(size_t)(j + 1) * NB_SCAT] : (unsigned)E;
    unsigned blen  = end - start;
    unsigned csz   = (blen + nsplit - 1) / nsplit;
    unsigned ss    = start + (unsigned)sp * csz;
    unsigned se    = min(end, ss + csz);

    for (unsigned i0 = ss + t; i0 < se; i0 += 4u * 256u) {
        unsigned meta[4]; float4 ea[4]; bool act[4];
#pragma unroll
        for (int u = 0; u < 4; ++u) {
            unsigned i = i0 + (unsigned)u * 256u;
            act[u] = (i < se);
            if (act[u]) { meta[u] = rec_meta[i]; ea[u] = rec_ea[i]; }
        }
        float4 n0[4], n1[4];
#pragma unroll
        for (int u = 0; u < 4; ++u)
            if (act[u]) {
                size_t s = meta[u] & 0x3FFFFu;
                n0[u] = napack[2 * s];
                n1[u] = napack[2 * s + 1];
            }
#pragma unroll
        for (int u = 0; u < 4; ++u) {
            if (!act[u]) continue;
            int dl = meta[u] >> 18;
            const float* pr = &pdl[dl * 12];
            float4 p0 = *reinterpret_cast<const float4*>(pr);
            float4 p1 = *reinterpret_cast<const float4*>(pr + 4);
            float2 p2 = *reinterpret_cast<const float2*>(pr + 8);
            float m[DM] = {p0.x, p0.y, p0.z, p0.w, p1.x, p1.y, p1.z, p1.w, p2.x, p2.y};
            float a0 = n0[u].x, a1 = n0[u].y, a2 = n0[u].z, a3 = n0[u].w, a4 = n1[u].x;
            float4 e4 = ea[u];
#pragma unroll
            for (int q = 0; q < DM; ++q) {
                float v = m[q];
                v = fmaf(a0, sws[q],        v);
                v = fmaf(a1, sws[10 + q],   v);
                v = fmaf(a2, sws[20 + q],   v);
                v = fmaf(a3, sws[30 + q],   v);
                v = fmaf(a4, sws[40 + q],   v);
                v = fmaf(e4.x, swe[q],      v);
                v = fmaf(e4.y, swe[10 + q], v);
                v = fmaf(e4.z, swe[20 + q], v);
                v = fmaf(e4.w, swe[30 + q], v);
                if (v > 0.f) atomicAdd(&acc[dl * DM + q], v);  // ds_add_f32
            }
        }
    }
    __syncthreads();

    float* dst = xpart + (size_t)sp * xstride + (size_t)nb0 * DM;
    for (int i = t; i < BKT_NODES * DM; i += 256) dst[i] = acc[i];
}

// ---------------------------------------------------------------------------
// C: combine partials + node-MLP head + wave-segmented pooling into gacc
// ---------------------------------------------------------------------------
__global__ __launch_bounds__(256) void combine_kernel(
    const float* __restrict__ xpart, size_t xstride,
    const int* __restrict__ batch,
    const float* __restrict__ w1, const float* __restrict__ b1,
    const float* __restrict__ w2, const float* __restrict__ b2,
    float* __restrict__ gacc, int N, int nsplit)
{
    __shared__ float s1[100], sb1[10], s2[50], sb2[5];
    int t = threadIdx.x;
    if (t < 100)      s1[t] = w1[t];
    else if (t < 110) sb1[t - 100] = b1[t - 100];
    else if (t < 160) s2[t - 110] = w2[t - 110];
    else if (t < 165) sb2[t - 160] = b2[t - 160];
    __syncthreads();

    int n = blockIdx.x * blockDim.x + t;
    bool valid = (n < N);
    int g = 0x7fffffff;
    float h2[5] = {0.f, 0.f, 0.f, 0.f, 0.f};

    if (valid) {
        float x[DM];
#pragma unroll
        for (int q = 0; q < DM; ++q) x[q] = 0.f;
        for (int sp = 0; sp < nsplit; ++sp) {
            const float2* row = reinterpret_cast<const float2*>(
                xpart + (size_t)sp * xstride + (size_t)n * DM);
#pragma unroll
            for (int h = 0; h < 5; ++h) {
                float2 v = row[h];
                x[2 * h] += v.x; x[2 * h + 1] += v.y;
            }
        }

        float h1[10];
#pragma unroll
        for (int q = 0; q < 10; ++q) h1[q] = sb1[q];
#pragma unroll
        for (int k = 0; k < 10; ++k)
#pragma unroll
            for (int q = 0; q < 10; ++q) h1[q] = fmaf(x[k], s1[k * 10 + q], h1[q]);
#pragma unroll
        for (int q = 0; q < 10; ++q) h1[q] = fmaxf(h1[q], 0.f);
#pragma unroll
        for (int q = 0; q < 5; ++q) h2[q] = sb2[q];
#pragma unroll
        for (int k = 0; k < 10; ++k)
#pragma unroll
            for (int q = 0; q < 5; ++q) h2[q] = fmaf(h1[k], s2[k * 5 + q], h2[q]);
#pragma unroll
        for (int q = 0; q < 5; ++q) h2[q] = fmaxf(h2[q], 0.f);
        g = batch[n];
    }

    int lane = t & 63;
#pragma unroll
    for (int o = 1; o < 64; o <<= 1) {
        int go = __shfl_down(g, o);
        float v0 = __shfl_down(h2[0], o);
        float v1 = __shfl_down(h2[1], o);
        float v2 = __shfl_down(h2[2], o);
        float v3 = __shfl_down(h2[3], o);
        float v4 = __shfl_down(h2[4], o);
        if (lane + o < 64 && go == g) {
            h2[0] += v0; h2[1] += v1; h2[2] += v2; h2[3] += v3; h2[4] += v4;
        }
    }
    int gp = __shfl_up(g, 1);
    bool head = (lane == 0) || (gp != g);
    if (head && g != 0x7fffffff) {
#pragma unroll
        for (int q = 0; q < 5; ++q)
            if (h2[q] != 0.f) unsafeAtomicAdd(&gacc[(size_t)g * 5 + q], h2[q]);
    }
}

// ---------------------------------------------------------------------------
// k4: per-graph head
// ---------------------------------------------------------------------------
__global__ __launch_bounds__(256) void graph_head_kernel(
    const float* __restrict__ gacc,
    const float* __restrict__ w3, const float* __restrict__ b3,
    const float* __restrict__ w4, const float* __restrict__ b4,
    float* __restrict__ out, int G)
{
    __shared__ float s3[25], sb3[5], s4[5], sb4[1];
    int t = threadIdx.x;
    if (t < 25)       s3[t] = w3[t];
    else if (t < 30)  sb3[t - 25] = b3[t - 25];
    else if (t < 35)  s4[t - 30] = w4[t - 30];
    else if (t == 35) sb4[0] = b4[0];
    __syncthreads();

    int g = blockIdx.x * blockDim.x + t;
    if (g >= G) return;

    float x[5];
#pragma unroll
    for (int k = 0; k < 5; ++k) x[k] = gacc[(size_t)g * 5 + k];

    float o = sb4[0];
#pragma unroll
    for (int q = 0; q < 5; ++q) {
        float h = sb3[q];
#pragma unroll
        for (int k = 0; k < 5; ++k) h = fmaf(x[k], s3[k * 5 + q], h);
        h = fmaxf(h, 0.f);
        o = fmaf(h, s4[q], o);
    }
    out[g] = o;
}

// ---------------------------------------------------------------------------
extern "C" void kernel_launch(void* const* d_in, const int* in_sizes, int n_in,
                              void* d_out, int out_size, void* d_ws, size_t ws_size,
                              hipStream_t stream)
{
    const int*   ei        = (const int*)d_in[0];
    const float* node_attr = (const float*)d_in[1];
    const float* edge_attr = (const float*)d_in[2];
    const int*   batch     = (const int*)d_in[3];
    const float* w_mpl = (const float*)d_in[5];
    const float* b_mpl = (const float*)d_in[6];
    const float* w1    = (const float*)d_in[7];
    const float* b1    = (const float*)d_in[8];
    const float* w2    = (const float*)d_in[9];
    const float* b2    = (const float*)d_in[10];
    const float* w3    = (const float*)d_in[11];
    const float* b3    = (const float*)d_in[12];
    const float* w4    = (const float*)d_in[13];
    const float* b4    = (const float*)d_in[14];
    float* out = (float*)d_out;

    const int E = in_sizes[0] / 2;
    const int N = in_sizes[1] / DN;
    const int G = out_size;

    const int nbk   = (N + BKT_NODES - 1) / BKT_NODES;     // 782
    const int chunk = (E + NB_SCAT - 1) / NB_SCAT;         // 12500
    const int len   = nbk * NB_SCAT;                       // 400384
    const int nsb   = (len + 255) / 256;                   // 1564 (<=4096)

    // workspace layout
    char* p = (char*)d_ws;
    float4*   rec_ea   = (float4*)p;   p += (size_t)E * 16;
    float4*   napack   = (float4*)p;   p += (size_t)N * 32;
    unsigned* rec_meta = (unsigned*)p; p += (size_t)E * 4;
    unsigned* cnt      = (unsigned*)p; p += (size_t)len * 4;
    unsigned* bsum     = (unsigned*)p; p += (size_t)((nsb + 3) & ~3) * 4;
    float*    gacc     = (float*)p;    p += (size_t)G * 5 * 4;
    float*    xpart    = (float*)p;

    // pick nsplit per available workspace (deterministic in ws_size)
    size_t used = (size_t)(p - (char*)d_ws);
    size_t xstride = (size_t)nbk * BKT_NODES * DM;         // floats per split
    int nsplit = 8;
    while (nsplit > 1 && used + (size_t)nsplit * xstride * 4 > ws_size) nsplit >>= 1;

    hipMemsetAsync(gacc, 0, (size_t)G * 5 * 4, stream);

    pack_kernel<<<(N + 255) / 256, 256, 0, stream>>>(node_attr, napack, N);
    hist_kernel<<<NB_SCAT, 256, 0, stream>>>(ei, cnt, E, chunk, nbk);
    scan1_kernel<<<nsb, 256, 0, stream>>>(cnt, bsum, len);
    scan2_kernel<<<1, 1024, 0, stream>>>(bsum, nsb);
    scan3_kernel<<<nsb, 256, 0, stream>>>(cnt, bsum, len);
    scatter_kernel<<<NB_SCAT, 256, 0, stream>>>(ei, edge_attr, cnt, rec_meta, rec_ea, E, chunk, nbk);
    gather_kernel<<<nbk * nsplit, 256, 0, stream>>>(rec_meta, rec_ea, cnt, napack,
                                                    w_mpl, b_mpl, xpart, xstride, E, N, nbk, nsplit);
    combine_kernel<<<nbk, 256, 0, stream>>>(xpart, xstride, batch, w1, b1, w2, b2, gacc, N, nsplit);
    graph_head_kernel<<<(G + 255) / 256, 256, 0, stream>>>(gacc, w3, b3, w4, b4, out, G);
}

// Round 5
// 585.122 us; speedup vs baseline: 3.0478x; 1.0626x over previous
//
#include <hip/hip_runtime.h>

#define DN 5
#define DE 4
#define DM 10
#define NB 2048               // hist/scatter blocks
#define BKT_SH 8              // bucket = dst >> 8  (256 nodes / bucket)
#define BKT_NODES 256
#define MAXBKT 1024           // LDS hist capacity (nbk=782 for N=200k)

// ---------------------------------------------------------------------------
// H: fused node-pack + per-block bucket histogram.
//    napack[n] = 32B-aligned node_attr row; cnt[bucket][block] = count.
// ---------------------------------------------------------------------------
__global__ __launch_bounds__(256) void hist_pack_kernel(
    const int* __restrict__ ei, const float* __restrict__ node_attr,
    float4* __restrict__ napack, unsigned* __restrict__ cnt,
    int E, int chunk, int nbk, int N)
{
    __shared__ unsigned hist[MAXBKT];
    int t = threadIdx.x, b = blockIdx.x;

    // pack a slice of nodes (independent of hist work)
    int n = b * 256 + t;
    if (n < N) {
        const float* r = node_attr + (size_t)n * DN;
        napack[2 * (size_t)n]     = make_float4(r[0], r[1], r[2], r[3]);
        napack[2 * (size_t)n + 1] = make_float4(r[4], 0.f, 0.f, 0.f);
    }

    for (int j = t; j < nbk; j += 256) hist[j] = 0;
    __syncthreads();

    int e0 = b * chunk, e1 = min(E, e0 + chunk);
    for (int i = e0 + t; i < e1; i += 256) {
        int d = ei[(size_t)E + i];
        atomicAdd(&hist[d >> BKT_SH], 1u);
    }
    __syncthreads();
    for (int j = t; j < nbk; j += 256)
        cnt[(size_t)j * NB + b] = hist[j];
}

// ---------------------------------------------------------------------------
// R: per-bucket row scan: cnt[j][0..NB-1] -> exclusive prefix; rowtotal[j]=sum
// ---------------------------------------------------------------------------
__global__ __launch_bounds__(256) void scan_rows_kernel(
    unsigned* __restrict__ cnt, unsigned* __restrict__ rowtotal)
{
    __shared__ unsigned lds[256];
    int j = blockIdx.x, t = threadIdx.x;
    unsigned* row = cnt + (size_t)j * NB;

    unsigned v[8], s = 0;
#pragma unroll
    for (int u = 0; u < 8; ++u) { v[u] = row[t * 8 + u]; s += v[u]; }
    lds[t] = s; __syncthreads();
#pragma unroll
    for (int o = 1; o < 256; o <<= 1) {
        unsigned add = (t >= o) ? lds[t - o] : 0u;
        __syncthreads();
        lds[t] += add;
        __syncthreads();
    }
    unsigned excl = lds[t] - s;
#pragma unroll
    for (int u = 0; u < 8; ++u) { row[t * 8 + u] = excl; excl += v[u]; }
    if (t == 255) rowtotal[j] = lds[255];
}

// ---------------------------------------------------------------------------
// B: exclusive scan of rowtotal[0..nbk-1] -> gbase[0..nbk] (gbase[nbk]=E)
// ---------------------------------------------------------------------------
__global__ __launch_bounds__(1024) void scan_base_kernel(
    const unsigned* __restrict__ rowtotal, unsigned* __restrict__ gbase,
    int nbk, int E)
{
    __shared__ unsigned lds[1024];
    int t = threadIdx.x;
    unsigned v = (t < nbk) ? rowtotal[t] : 0u;
    lds[t] = v; __syncthreads();
#pragma unroll
    for (int o = 1; o < 1024; o <<= 1) {
        unsigned add = (t >= o) ? lds[t - o] : 0u;
        __syncthreads();
        lds[t] += add;
        __syncthreads();
    }
    unsigned excl = lds[t] - v;
    if (t < nbk)       gbase[t] = excl;
    else if (t == nbk) gbase[t] = (unsigned)E;
}

// ---------------------------------------------------------------------------
// S: scatter edges to bucket-sorted 32B records (one sector per record).
//    rec4[2p]   = (meta, ea.x, ea.y, ea.z) ; rec4[2p+1] = (ea.w, 0,0,0)
//    meta = src | (dst&255)<<18
// ---------------------------------------------------------------------------
__global__ __launch_bounds__(256) void scatter_kernel(
    const int* __restrict__ ei, const float* __restrict__ edge_attr,
    const unsigned* __restrict__ cnt, const unsigned* __restrict__ gbase,
    float4* __restrict__ rec4, int E, int chunk, int nbk)
{
    __shared__ unsigned woff[MAXBKT];
    int t = threadIdx.x, b = blockIdx.x;
    for (int j = t; j < nbk; j += 256)
        woff[j] = gbase[j] + cnt[(size_t)j * NB + b];
    __syncthreads();

    int e0 = b * chunk, e1 = min(E, e0 + chunk);
    for (int i0 = e0 + t; i0 < e1; i0 += 4 * 256) {
        int s[4], d[4]; float4 ea[4]; bool act[4];
#pragma unroll
        for (int u = 0; u < 4; ++u) {
            int i = i0 + u * 256;
            act[u] = (i < e1);
            if (act[u]) {
                s[u] = ei[i];
                d[u] = ei[(size_t)E + i];
                ea[u] = reinterpret_cast<const float4*>(edge_attr)[i];
            }
        }
#pragma unroll
        for (int u = 0; u < 4; ++u) {
            if (!act[u]) continue;
            unsigned p = atomicAdd(&woff[d[u] >> BKT_SH], 1u);
            unsigned meta = (unsigned)s[u] | ((unsigned)(d[u] & 255) << 18);
            rec4[2 * (size_t)p]     = make_float4(__uint_as_float(meta), ea[u].x, ea[u].y, ea[u].z);
            rec4[2 * (size_t)p + 1] = make_float4(ea[u].w, 0.f, 0.f, 0.f);
        }
    }
}

// ---------------------------------------------------------------------------
// G: per-(bucket,split) gather. Gathers raw napack[src] (6.4 MB table),
//    computes both projections in-kernel, accumulates via LDS f32 atomics,
//    writes contiguous partial tile.  4-edge software pipeline per thread.
// ---------------------------------------------------------------------------
__global__ __launch_bounds__(256) void gather_kernel(
    const float4* __restrict__ rec4, const unsigned* __restrict__ gbase,
    const float4* __restrict__ napack,
    const float* __restrict__ w_mpl, const float* __restrict__ b_mpl,
    float* __restrict__ xpart, size_t xstride,
    int E, int N, int nbk, int nsplit)
{
    __shared__ float acc[BKT_NODES * DM];      // 10 KB
    __shared__ float pdl[BKT_NODES * 12];      // 12 KB (48B rows)
    __shared__ float sws[50];                  // W_src
    __shared__ float swe[40];                  // W_edge

    int t = threadIdx.x;
    int j  = blockIdx.x / nsplit;
    int sp = blockIdx.x - j * nsplit;
    int nb0 = j * BKT_NODES;

    if (t < 50)       sws[t] = w_mpl[t];
    else if (t < 90)  swe[t - 50] = w_mpl[100 + (t - 50)];

    for (int i = t; i < BKT_NODES * DM; i += 256) acc[i] = 0.f;

    // stage dst-projection tile (bias folded in): one row per thread
    {
        int n = nb0 + t;
        float a0 = 0.f, a1 = 0.f, a2 = 0.f, a3 = 0.f, a4 = 0.f;
        if (n < N) {
            float4 r0 = napack[2 * (size_t)n];
            float4 r1 = napack[2 * (size_t)n + 1];
            a0 = r0.x; a1 = r0.y; a2 = r0.z; a3 = r0.w; a4 = r1.x;
        }
#pragma unroll
        for (int q = 0; q < DM; ++q) {
            float v = b_mpl[q];
            v = fmaf(a0, w_mpl[50 + q], v);
            v = fmaf(a1, w_mpl[60 + q], v);
            v = fmaf(a2, w_mpl[70 + q], v);
            v = fmaf(a3, w_mpl[80 + q], v);
            v = fmaf(a4, w_mpl[90 + q], v);
            pdl[t * 12 + q] = v;
        }
    }
    __syncthreads();

    unsigned start = gbase[j];
    unsigned end   = gbase[j + 1];
    unsigned blen  = end - start;
    unsigned csz   = (blen + nsplit - 1) / nsplit;
    unsigned ss    = start + (unsigned)sp * csz;
    unsigned se    = min(end, ss + csz);

    for (unsigned i0 = ss + t; i0 < se; i0 += 4u * 256u) {
        float4 r0[4], r1[4]; bool act[4];
#pragma unroll
        for (int u = 0; u < 4; ++u) {
            unsigned i = i0 + (unsigned)u * 256u;
            act[u] = (i < se);
            if (act[u]) { r0[u] = rec4[2 * (size_t)i]; r1[u] = rec4[2 * (size_t)i + 1]; }
        }
        float4 n0[4], n1[4];
#pragma unroll
        for (int u = 0; u < 4; ++u)
            if (act[u]) {
                size_t s = __float_as_uint(r0[u].x) & 0x3FFFFu;
                n0[u] = napack[2 * s];
                n1[u] = napack[2 * s + 1];
            }
#pragma unroll
        for (int u = 0; u < 4; ++u) {
            if (!act[u]) continue;
            unsigned meta = __float_as_uint(r0[u].x);
            int dl = meta >> 18;
            const float* pr = &pdl[dl * 12];
            float4 p0 = *reinterpret_cast<const float4*>(pr);
            float4 p1 = *reinterpret_cast<const float4*>(pr + 4);
            float2 p2 = *reinterpret_cast<const float2*>(pr + 8);
            float m[DM] = {p0.x, p0.y, p0.z, p0.w, p1.x, p1.y, p1.z, p1.w, p2.x, p2.y};
            float a0 = n0[u].x, a1 = n0[u].y, a2 = n0[u].z, a3 = n0[u].w, a4 = n1[u].x;
            float e0 = r0[u].y, e1 = r0[u].z, e2 = r0[u].w, e3 = r1[u].x;
#pragma unroll
            for (int q = 0; q < DM; ++q) {
                float v = m[q];
                v = fmaf(a0, sws[q],      v);
                v = fmaf(a1, sws[10 + q], v);
                v = fmaf(a2, sws[20 + q], v);
                v = fmaf(a3, sws[30 + q], v);
                v = fmaf(a4, sws[40 + q], v);
                v = fmaf(e0, swe[q],      v);
                v = fmaf(e1, swe[10 + q], v);
                v = fmaf(e2, swe[20 + q], v);
                v = fmaf(e3, swe[30 + q], v);
                if (v > 0.f) atomicAdd(&acc[dl * DM + q], v);  // ds_add_f32
            }
        }
    }
    __syncthreads();

    float* dst = xpart + (size_t)sp * xstride + (size_t)nb0 * DM;
    for (int i = t; i < BKT_NODES * DM; i += 256) dst[i] = acc[i];
}

// ---------------------------------------------------------------------------
// C: combine partials + node-MLP head + wave-segmented pooling into gacc
// ---------------------------------------------------------------------------
__global__ __launch_bounds__(256) void combine_kernel(
    const float* __restrict__ xpart, size_t xstride,
    const int* __restrict__ batch,
    const float* __restrict__ w1, const float* __restrict__ b1,
    const float* __restrict__ w2, const float* __restrict__ b2,
    float* __restrict__ gacc, int N, int nsplit)
{
    __shared__ float s1[100], sb1[10], s2[50], sb2[5];
    int t = threadIdx.x;
    if (t < 100)      s1[t] = w1[t];
    else if (t < 110) sb1[t - 100] = b1[t - 100];
    else if (t < 160) s2[t - 110] = w2[t - 110];
    else if (t < 165) sb2[t - 160] = b2[t - 160];
    __syncthreads();

    int n = blockIdx.x * blockDim.x + t;
    bool valid = (n < N);
    int g = 0x7fffffff;
    float h2[5] = {0.f, 0.f, 0.f, 0.f, 0.f};

    if (valid) {
        float x[DM];
#pragma unroll
        for (int q = 0; q < DM; ++q) x[q] = 0.f;
        for (int sp = 0; sp < nsplit; ++sp) {
            const float2* row = reinterpret_cast<const float2*>(
                xpart + (size_t)sp * xstride + (size_t)n * DM);
#pragma unroll
            for (int h = 0; h < 5; ++h) {
                float2 v = row[h];
                x[2 * h] += v.x; x[2 * h + 1] += v.y;
            }
        }

        float h1[10];
#pragma unroll
        for (int q = 0; q < 10; ++q) h1[q] = sb1[q];
#pragma unroll
        for (int k = 0; k < 10; ++k)
#pragma unroll
            for (int q = 0; q < 10; ++q) h1[q] = fmaf(x[k], s1[k * 10 + q], h1[q]);
#pragma unroll
        for (int q = 0; q < 10; ++q) h1[q] = fmaxf(h1[q], 0.f);
#pragma unroll
        for (int q = 0; q < 5; ++q) h2[q] = sb2[q];
#pragma unroll
        for (int k = 0; k < 10; ++k)
#pragma unroll
            for (int q = 0; q < 5; ++q) h2[q] = fmaf(h1[k], s2[k * 5 + q], h2[q]);
#pragma unroll
        for (int q = 0; q < 5; ++q) h2[q] = fmaxf(h2[q], 0.f);
        g = batch[n];
    }

    int lane = t & 63;
#pragma unroll
    for (int o = 1; o < 64; o <<= 1) {
        int go = __shfl_down(g, o);
        float v0 = __shfl_down(h2[0], o);
        float v1 = __shfl_down(h2[1], o);
        float v2 = __shfl_down(h2[2], o);
        float v3 = __shfl_down(h2[3], o);
        float v4 = __shfl_down(h2[4], o);
        if (lane + o < 64 && go == g) {
            h2[0] += v0; h2[1] += v1; h2[2] += v2; h2[3] += v3; h2[4] += v4;
        }
    }
    int gp = __shfl_up(g, 1);
    bool head = (lane == 0) || (gp != g);
    if (head && g != 0x7fffffff) {
#pragma unroll
        for (int q = 0; q < 5; ++q)
            if (h2[q] != 0.f) unsafeAtomicAdd(&gacc[(size_t)g * 5 + q], h2[q]);
    }
}

// ---------------------------------------------------------------------------
// k4: per-graph head
// ---------------------------------------------------------------------------
__global__ __launch_bounds__(256) void graph_head_kernel(
    const float* __restrict__ gacc,
    const float* __restrict__ w3, const float* __restrict__ b3,
    const float* __restrict__ w4, const float* __restrict__ b4,
    float* __restrict__ out, int G)
{
    __shared__ float s3[25], sb3[5], s4[5], sb4[1];
    int t = threadIdx.x;
    if (t < 25)       s3[t] = w3[t];
    else if (t < 30)  sb3[t - 25] = b3[t - 25];
    else if (t < 35)  s4[t - 30] = w4[t - 30];
    else if (t == 35) sb4[0] = b4[0];
    __syncthreads();

    int g = blockIdx.x * blockDim.x + t;
    if (g >= G) return;

    float x[5];
#pragma unroll
    for (int k = 0; k < 5; ++k) x[k] = gacc[(size_t)g * 5 + k];

    float o = sb4[0];
#pragma unroll
    for (int q = 0; q < 5; ++q) {
        float h = sb3[q];
#pragma unroll
        for (int k = 0; k < 5; ++k) h = fmaf(x[k], s3[k * 5 + q], h);
        h = fmaxf(h, 0.f);
        o = fmaf(h, s4[q], o);
    }
    out[g] = o;
}

// ---------------------------------------------------------------------------
extern "C" void kernel_launch(void* const* d_in, const int* in_sizes, int n_in,
                              void* d_out, int out_size, void* d_ws, size_t ws_size,
                              hipStream_t stream)
{
    const int*   ei        = (const int*)d_in[0];
    const float* node_attr = (const float*)d_in[1];
    const float* edge_attr = (const float*)d_in[2];
    const int*   batch     = (const int*)d_in[3];
    const float* w_mpl = (const float*)d_in[5];
    const float* b_mpl = (const float*)d_in[6];
    const float* w1    = (const float*)d_in[7];
    const float* b1    = (const float*)d_in[8];
    const float* w2    = (const float*)d_in[9];
    const float* b2    = (const float*)d_in[10];
    const float* w3    = (const float*)d_in[11];
    const float* b3    = (const float*)d_in[12];
    const float* w4    = (const float*)d_in[13];
    const float* b4    = (const float*)d_in[14];
    float* out = (float*)d_out;

    const int E = in_sizes[0] / 2;
    const int N = in_sizes[1] / DN;
    const int G = out_size;

    const int nbk   = (N + BKT_NODES - 1) / BKT_NODES;     // 782
    const int chunk = (E + NB - 1) / NB;                   // 3125

    // workspace layout (xpart aliases cnt: cnt is dead once scatter completes)
    char* p = (char*)d_ws;
    float4*   rec4     = (float4*)p;   p += (size_t)E * 32;
    float4*   napack   = (float4*)p;   p += (size_t)N * 32;
    unsigned* rowtotal = (unsigned*)p; p += ((size_t)nbk * 4 + 15) & ~15ull;
    unsigned* gbase    = (unsigned*)p; p += ((size_t)(nbk + 1) * 4 + 15) & ~15ull;
    float*    gacc     = (float*)p;    p += (size_t)G * 5 * 4;
    unsigned* cnt      = (unsigned*)p;
    float*    xpart    = (float*)p;    // same base as cnt (sequential reuse)
    size_t cnt_bytes = (size_t)nbk * NB * 4;

    // pick nsplit per available workspace (deterministic in ws_size)
    size_t used = (size_t)((char*)cnt - (char*)d_ws);
    size_t xstride = (size_t)nbk * BKT_NODES * DM;         // floats per split
    int nsplit = 8;
    while (nsplit > 1 &&
           used + ((cnt_bytes > (size_t)nsplit * xstride * 4) ? cnt_bytes
                                                              : (size_t)nsplit * xstride * 4) > ws_size)
        nsplit >>= 1;

    hipMemsetAsync(gacc, 0, (size_t)G * 5 * 4, stream);

    hist_pack_kernel<<<NB, 256, 0, stream>>>(ei, node_attr, napack, cnt, E, chunk, nbk, N);
    scan_rows_kernel<<<nbk, 256, 0, stream>>>(cnt, rowtotal);
    scan_base_kernel<<<1, 1024, 0, stream>>>(rowtotal, gbase, nbk, E);
    scatter_kernel<<<NB, 256, 0, stream>>>(ei, edge_attr, cnt, gbase, rec4, E, chunk, nbk);
    gather_kernel<<<nbk * nsplit, 256, 0, stream>>>(rec4, gbase, napack, w_mpl, b_mpl,
                                                    xpart, xstride, E, N, nbk, nsplit);
    combine_kernel<<<nbk, 256, 0, stream>>>(xpart, xstride, batch, w1, b1, w2, b2, gacc, N, nsplit);
    graph_head_kernel<<<(G + 255) / 256, 256, 0, stream>>>(gacc, w3, b3, w4, b4, out, G);
}